// Round 2
// baseline (1010.254 us; speedup 1.0000x reference)
//
#include <hip/hip_runtime.h>

#define NB 2048
#define LSEQ 50
#define EMB 128
#define CUT0 12500
#define HEADN 12502
#define N0 12500
#define N1 25000
#define OUTW 50000

typedef unsigned short ushort_t;
typedef short short8 __attribute__((ext_vector_type(8)));
typedef float f32x4 __attribute__((ext_vector_type(4)));

// f32 -> bf16 round-to-nearest-even (no NaN handling needed: inputs are finite)
__device__ inline ushort_t f2bf(float f){
  union { float f; unsigned int u; } v; v.f = f;
  unsigned int u = v.u;
  unsigned int r = (u + 0x7FFFu + ((u >> 16) & 1u)) >> 16;
  return (ushort_t)r;
}

// ---------------------------------------------------------------------------
// Pool: per row, masked mean of gathered embeddings; also h0 = pooled@t0_proj^T,
// h1 = pooled@t1_proj^T (stored bf16), and the two exact f32 head bias logits.
// ---------------------------------------------------------------------------
__global__ __launch_bounds__(128) void pool_kernel(
    const int* __restrict__ x, const float* __restrict__ emb,
    const float* __restrict__ t0p, const float* __restrict__ t1p,
    const float* __restrict__ hw,
    ushort_t* __restrict__ pooledb, ushort_t* __restrict__ h0,
    ushort_t* __restrict__ h1, float* __restrict__ head2)
{
  __shared__ int ids[LSEQ];
  __shared__ float prow[EMB];
  const int b = blockIdx.x, tid = threadIdx.x;
  if (tid < LSEQ) ids[tid] = x[b * LSEQ + tid];
  __syncthreads();
  float acc = 0.f; int cnt = 0;
  for (int t = 0; t < LSEQ; t++) {
    int id = ids[t];
    if (id != 0) { cnt++; acc += emb[(size_t)id * EMB + tid]; }
  }
  float p = acc / (float)(cnt > 0 ? cnt : 1);
  prow[tid] = p;
  pooledb[b * EMB + tid] = f2bf(p);
  __syncthreads();
  if (tid < 64) {
    const float* wr = t0p + tid * EMB;
    float s = 0.f;
    #pragma unroll 8
    for (int k = 0; k < EMB; k++) s += prow[k] * wr[k];
    h0[b * 64 + tid] = f2bf(s);
  } else if (tid < 96) {
    const float* wr = t1p + (tid - 64) * EMB;
    float s = 0.f;
    #pragma unroll 8
    for (int k = 0; k < EMB; k++) s += prow[k] * wr[k];
    h1[b * 32 + (tid - 64)] = f2bf(s);
  } else if (tid < 98) {
    const float* wr = hw + (size_t)(CUT0 + (tid - 96)) * EMB;
    float s = 0.f;
    #pragma unroll 8
    for (int k = 0; k < EMB; k++) s += prow[k] * wr[k];
    head2[b * 2 + (tid - 96)] = s;
  }
}

// ---------------------------------------------------------------------------
// Weight convert f32 -> bf16 (padding rows already zeroed by memsetAsync)
// ---------------------------------------------------------------------------
__global__ void convert_kernel(const float* __restrict__ hw,
                               const float* __restrict__ t0o,
                               const float* __restrict__ t1o,
                               ushort_t* __restrict__ whb,
                               ushort_t* __restrict__ t0b,
                               ushort_t* __restrict__ t1b)
{
  const int nH = HEADN * EMB;          // 1600256
  const int n0 = N0 * 64;              // 800000
  const int n1 = N1 * 32;              // 800000
  const int total = nH + n0 + n1;
  for (int i = blockIdx.x * blockDim.x + threadIdx.x; i < total;
       i += gridDim.x * blockDim.x) {
    if (i < nH)            whb[i] = f2bf(hw[i]);
    else if (i < nH + n0)  t0b[i - nH] = f2bf(t0o[i - nH]);
    else                   t1b[i - nH - n0] = f2bf(t1o[i - nH - n0]);
  }
}

// ---------------------------------------------------------------------------
// LSE fold: per-row additive constants for the three output branches
// ---------------------------------------------------------------------------
__global__ void lse_kernel(const float* __restrict__ sums,
                           const float* __restrict__ head2,
                           float* __restrict__ negLseH,
                           float* __restrict__ c0c, float* __restrict__ c1c)
{
  int b = blockIdx.x * blockDim.x + threadIdx.x;
  if (b < NB) {
    float lh = logf(sums[b]);
    negLseH[b] = -lh;
    c0c[b] = head2[2 * b]     - lh - logf(sums[NB + b]);
    c1c[b] = head2[2 * b + 1] - lh - logf(sums[2 * NB + b]);
  }
}

// ---------------------------------------------------------------------------
// Tiled bf16 MFMA GEMM, NT layout (A: M x K row-major, B: Npad x K row-major).
// BM=BN=128, 4 waves (2x2 of 64x64). Full K resident in LDS (K<=128).
// Staging: global_load_lds width 16, source-side XOR swizzle (rule #21) so
// fragment ds_read_b128 is ~conflict-free.
// EPI=0: per-row sum(exp(logit)) for col<N via shfl butterfly + atomicAdd.
// EPI=1: out[row*OUTW + outOff + col] = logit + addv[row] for col<N.
// ---------------------------------------------------------------------------
template<int K, int EPI>
__global__ __launch_bounds__(256, 2) void gemm_k(
    const ushort_t* __restrict__ A, const ushort_t* __restrict__ Bw,
    int N, float* __restrict__ sums,
    const float* __restrict__ addv, float* __restrict__ out, int outOff)
{
  constexpr int RSL = (K == 128) ? 8 : ((K == 64) ? 7 : 6); // log2(row bytes)
  constexpr int RS  = 1 << RSL;
  constexpr int SW  = (K == 32) ? 3 : 7;                    // swizzle row mask

  __shared__ ushort_t As[128 * K];
  __shared__ ushort_t Bs[128 * K];

  const int tid  = threadIdx.x;
  const int w    = tid >> 6;
  const int lane = tid & 63;
  const int colTile = blockIdx.x, rowTile = blockIdx.y;

  // ---- stage A and B tiles (each contiguous 128*K elements in global) ----
  constexpr int CHUNKS = (128 * K * 2) / 1024; // 1KB wave-issues per matrix
  constexpr int CPW    = CHUNKS / 4;
  {
    const char* Ag = (const char*)(A  + (size_t)rowTile * (128 * K));
    const char* Bg = (const char*)(Bw + (size_t)colTile * (128 * K));
    char* Al = (char*)As;
    char* Bl = (char*)Bs;
    #pragma unroll
    for (int i = 0; i < CPW; i++) {
      int chunk = w * CPW + i;
      int p = chunk * 1024 + lane * 16;      // linear LDS byte offset
      int r = p >> RSL;
      int c = p & (RS - 1);
      int src = (r << RSL) | (c ^ ((r & SW) << 4)); // inverse-swizzled source
      __builtin_amdgcn_global_load_lds(
          (const __attribute__((address_space(1))) void*)(Ag + src),
          (__attribute__((address_space(3))) void*)(Al + chunk * 1024), 16, 0, 0);
      __builtin_amdgcn_global_load_lds(
          (const __attribute__((address_space(1))) void*)(Bg + src),
          (__attribute__((address_space(3))) void*)(Bl + chunk * 1024), 16, 0, 0);
    }
  }
  __syncthreads();

  // ---- MFMA main loop ----
  f32x4 acc[4][4] = {};
  const int wr = w >> 1, wc = w & 1;
  const char* Alc = (const char*)As;
  const char* Blc = (const char*)Bs;
  #pragma unroll
  for (int kk = 0; kk < K / 32; kk++) {
    short8 a[4], b[4];
    const int kb = kk * 64 + (lane >> 4) * 16;
    #pragma unroll
    for (int m = 0; m < 4; m++) {
      int r = wr * 64 + m * 16 + (lane & 15);
      a[m] = *(const short8*)(Alc + ((r << RSL) | (kb ^ ((r & SW) << 4))));
    }
    #pragma unroll
    for (int n = 0; n < 4; n++) {
      int r = wc * 64 + n * 16 + (lane & 15);
      b[n] = *(const short8*)(Blc + ((r << RSL) | (kb ^ ((r & SW) << 4))));
    }
    #pragma unroll
    for (int m = 0; m < 4; m++)
      #pragma unroll
      for (int n = 0; n < 4; n++)
        acc[m][n] = __builtin_amdgcn_mfma_f32_16x16x32_bf16(a[m], b[n], acc[m][n], 0, 0, 0);
  }

  // ---- epilogue ----
  const int rowBase = rowTile * 128 + wr * 64;
  const int colBase = colTile * 128 + wc * 64;
  const int ln = lane & 15, lg = lane >> 4;
  if constexpr (EPI == 0) {
    #pragma unroll
    for (int m = 0; m < 4; m++) {
      #pragma unroll
      for (int j = 0; j < 4; j++) {
        float e = 0.f;
        #pragma unroll
        for (int n = 0; n < 4; n++) {
          int col = colBase + n * 16 + ln;
          if (col < N) e += __expf(acc[m][n][j]);
        }
        e += __shfl_xor(e, 1);
        e += __shfl_xor(e, 2);
        e += __shfl_xor(e, 4);
        e += __shfl_xor(e, 8);
        if (ln == 0) atomicAdd(&sums[rowBase + m * 16 + lg * 4 + j], e);
      }
    }
  } else {
    #pragma unroll
    for (int m = 0; m < 4; m++) {
      #pragma unroll
      for (int j = 0; j < 4; j++) {
        int row = rowBase + m * 16 + lg * 4 + j;
        float av = addv[row];
        #pragma unroll
        for (int n = 0; n < 4; n++) {
          int col = colBase + n * 16 + ln;
          if (col < N) out[(size_t)row * OUTW + outOff + col] = acc[m][n][j] + av;
        }
      }
    }
  }
}

// ---------------------------------------------------------------------------
// Workspace layout (bytes):
//   0        sums: 3*2048 f32 (head, t0, t1)                 24576
//   24576    whb : 12544*128 bf16 (zero-padded)            3211264
//   3235840  t0b : 12544*64  bf16                          1605632
//   4841472  t1b : 25088*32  bf16                          1605632
//   6447104  pooledb: 2048*128 bf16                         524288
//   6971392  h0  : 2048*64 bf16                             262144
//   7233536  h1  : 2048*32 bf16                             131072
//   7364608  head2: 2048*2 f32                               16384
//   7380992  negLseH / c0c / c1c: 3*2048 f32                 24576
// total ~7.4 MB; region [0, 6447104) zeroed each launch.
// ---------------------------------------------------------------------------
extern "C" void kernel_launch(void* const* d_in, const int* in_sizes, int n_in,
                              void* d_out, int out_size, void* d_ws, size_t ws_size,
                              hipStream_t stream)
{
  const int*   x       = (const int*)d_in[0];
  const float* emb     = (const float*)d_in[1];
  const float* head_w  = (const float*)d_in[2];
  const float* t0_proj = (const float*)d_in[3];
  const float* t0_out  = (const float*)d_in[4];
  const float* t1_proj = (const float*)d_in[5];
  const float* t1_out  = (const float*)d_in[6];
  float* out = (float*)d_out;
  char* w = (char*)d_ws;

  float*    sums    = (float*)(w + 0);
  ushort_t* whb     = (ushort_t*)(w + 24576);
  ushort_t* t0b     = (ushort_t*)(w + 3235840);
  ushort_t* t1b     = (ushort_t*)(w + 4841472);
  ushort_t* pooledb = (ushort_t*)(w + 6447104);
  ushort_t* h0      = (ushort_t*)(w + 6971392);
  ushort_t* h1      = (ushort_t*)(w + 7233536);
  float*    head2   = (float*)(w + 7364608);
  float*    negLseH = (float*)(w + 7380992);
  float*    c0c     = (float*)(w + 7389184);
  float*    c1c     = (float*)(w + 7397376);

  // zero atomics accumulators + padded weight region (ws is poisoned 0xAA)
  hipMemsetAsync(w, 0, 6447104, stream);

  pool_kernel<<<NB, 128, 0, stream>>>(x, emb, t0_proj, t1_proj, head_w,
                                      pooledb, h0, h1, head2);
  convert_kernel<<<2048, 256, 0, stream>>>(head_w, t0_out, t1_out, whb, t0b, t1b);

  // pass 1: sum(exp(logits)) per row
  gemm_k<128, 0><<<dim3(98, 16), 256, 0, stream>>>(pooledb, whb, HEADN, sums, nullptr, nullptr, 0);
  gemm_k< 64, 0><<<dim3(98, 16), 256, 0, stream>>>(h0, t0b, N0, sums + NB, nullptr, nullptr, 0);
  gemm_k< 32, 0><<<dim3(196, 16), 256, 0, stream>>>(h1, t1b, N1, sums + 2 * NB, nullptr, nullptr, 0);

  lse_kernel<<<(NB + 255) / 256, 256, 0, stream>>>(sums, head2, negLseH, c0c, c1c);

  // pass 2: recompute logits, add per-row constant, write output
  gemm_k<128, 1><<<dim3(98, 16), 256, 0, stream>>>(pooledb, whb, CUT0, nullptr, negLseH, out, 0);
  gemm_k< 64, 1><<<dim3(98, 16), 256, 0, stream>>>(h0, t0b, N0, nullptr, c0c, out, CUT0);
  gemm_k< 32, 1><<<dim3(196, 16), 256, 0, stream>>>(h1, t1b, N1, nullptr, c1c, out, 2 * CUT0);
}